// Round 4
// baseline (103.540 us; speedup 1.0000x reference)
//
#include <hip/hip_runtime.h>

// out[b,i,j] = s[b,i] * e[b,j] for 0 <= j - i <= 15, else 0.
// B=8, L=4096, fp32 out (512 MiB) -> pure write-BW-bound.
//
// One wave per row (16 x dwordx4 stores). Band-chunk e-loads are issued
// FIRST, then the independent zero stores drain (~1300 cy) while the loads
// complete, then the dependent band stores go last -> no mid-stream stall.

#define BAND 15
#define LDIM 4096
#define CHUNKS 16  // 4096 floats / (64 lanes * 4 floats/lane)

typedef float f32x4 __attribute__((ext_vector_type(4)));

__global__ __launch_bounds__(256) void band_outer_rows(
    const float* __restrict__ s,
    const float* __restrict__ e,
    float* __restrict__ out) {
  const int wave = threadIdx.x >> 6;
  const int lane = threadIdx.x & 63;
  const int row  = (blockIdx.x << 2) + wave;  // 0 .. 32767
  const int i    = row & (LDIM - 1);
  const int b    = row >> 12;

  const float sv = s[row];                    // wave-uniform broadcast load
  const float* __restrict__ eb = e + (b << 12);

  const int c_lo = i >> 8;                         // chunk holding column i
  const int c_hi = min((i + BAND) >> 8, CHUNKS - 1);  // chunk holding i+15 (clamped)

  // Issue the (at most 2) band-chunk loads up front; contiguous dwordx4/lane.
  const f32x4 ev_lo =
      *reinterpret_cast<const f32x4*>(eb + (c_lo << 8) + (lane << 2));
  const f32x4 ev_hi =
      *reinterpret_cast<const f32x4*>(eb + (c_hi << 8) + (lane << 2));

  f32x4* __restrict__ out4 =
      reinterpret_cast<f32x4*>(out) + (size_t)row * (LDIM / 4) + lane;

  // 14-15 independent zero stores: hide the load latency under store drain.
  const f32x4 z = {0.f, 0.f, 0.f, 0.f};
#pragma unroll
  for (int c = 0; c < CHUNKS; ++c) {
    if (c != c_lo && c != c_hi)                 // wave-uniform scalar branch
      __builtin_nontemporal_store(z, out4 + c * 64);
  }

  // Dependent band stores last.
  {
    const int j0 = (c_lo << 8) + (lane << 2);
    f32x4 v;
#pragma unroll
    for (int k = 0; k < 4; ++k) {
      const int j = j0 + k;
      v[k] = (j >= i && j - i <= BAND) ? sv * ev_lo[k] : 0.f;
    }
    __builtin_nontemporal_store(v, out4 + c_lo * 64);
  }
  if (c_hi != c_lo) {
    const int j0 = (c_hi << 8) + (lane << 2);
    f32x4 v;
#pragma unroll
    for (int k = 0; k < 4; ++k) {
      const int j = j0 + k;
      v[k] = (j >= i && j - i <= BAND) ? sv * ev_hi[k] : 0.f;
    }
    __builtin_nontemporal_store(v, out4 + c_hi * 64);
  }
}

extern "C" void kernel_launch(void* const* d_in, const int* in_sizes, int n_in,
                              void* d_out, int out_size, void* d_ws, size_t ws_size,
                              hipStream_t stream) {
  const float* s = (const float*)d_in[0];
  const float* e = (const float*)d_in[1];
  float* out = (float*)d_out;

  const int rows = out_size / LDIM;   // 32768; 4 waves (rows) per block
  band_outer_rows<<<rows / 4, 256, 0, stream>>>(s, e, out);
}

// Round 5
// 101.713 us; speedup vs baseline: 1.0180x; 1.0180x over previous
//
#include <hip/hip_runtime.h>

// out[b,i,j] = s[b,i] * e[b,j] for 0 <= j - i <= 15, else 0.
// B=8, L=4096, fp32 out (512 MiB) -> pure write-BW-bound.
//
// One wave (64 lanes) per output row: 16 dwordx4 stores of 1 KiB each.
// Row index i is wave-uniform -> band-chunk test is a scalar branch,
// at most 2 of 16 chunks take the band path.
//
// R4 A/B: PLAIN stores (no nontemporal). The harness's fillBufferAligned
// sustains 6.8 TB/s with plain stores on this chip; our nt version only
// reached 5.4 TB/s. Testing whether the nt flag is the 20% gap.

#define BAND 15
#define LDIM 4096
#define CHUNKS 16  // 4096 floats / (64 lanes * 4 floats/lane)

typedef float f32x4 __attribute__((ext_vector_type(4)));

__global__ __launch_bounds__(256) void band_outer_rows(
    const float* __restrict__ s,
    const float* __restrict__ e,
    float* __restrict__ out) {
  const int wave = threadIdx.x >> 6;
  const int lane = threadIdx.x & 63;
  const int row  = (blockIdx.x << 2) + wave;  // 0 .. 32767
  const int i    = row & (LDIM - 1);
  const int b    = row >> 12;

  const float sv = s[row];                    // wave-uniform broadcast load
  const float* __restrict__ eb = e + (b << 12);
  f32x4* __restrict__ out4 =
      reinterpret_cast<f32x4*>(out) + (size_t)row * (LDIM / 4) + lane;

  const int c_lo = i >> 8;            // first chunk touching the band
  const int c_hi = (i + BAND) >> 8;   // last chunk touching the band (may be 16 = none)

  const f32x4 z = {0.f, 0.f, 0.f, 0.f};
#pragma unroll
  for (int c = 0; c < CHUNKS; ++c) {
    if (c == c_lo || c == c_hi) {     // wave-uniform scalar branch
      const int j0 = (c << 8) + (lane << 2);
      f32x4 v;
#pragma unroll
      for (int k = 0; k < 4; ++k) {
        const int j = j0 + k;
        v[k] = (j >= i && j - i <= BAND) ? sv * eb[j] : 0.f;
      }
      out4[c * 64] = v;
    } else {
      out4[c * 64] = z;
    }
  }
}

extern "C" void kernel_launch(void* const* d_in, const int* in_sizes, int n_in,
                              void* d_out, int out_size, void* d_ws, size_t ws_size,
                              hipStream_t stream) {
  const float* s = (const float*)d_in[0];
  const float* e = (const float*)d_in[1];
  float* out = (float*)d_out;

  const int rows = out_size / LDIM;   // 32768; 4 waves (rows) per block
  band_outer_rows<<<rows / 4, 256, 0, stream>>>(s, e, out);
}